// Round 3
// baseline (1147.677 us; speedup 1.0000x reference)
//
#include <hip/hip_runtime.h>
#include <hip/hip_bf16.h>

// GAT 3-layer + pool + dense head for MI355X (gfx950).
// R3: k_agg replaced by k_gath — softmax folded inline (no max-subtraction:
// |alpha| < ~3 so exp is safe), no LDS/shuffles in the gather loop, U-deep
// unroll keeps ~16KB of loads in flight per wave (was latency-bound at ~3.4KB).

typedef __attribute__((ext_vector_type(8))) short short8;
typedef __attribute__((ext_vector_type(4))) float floatx4;

#define DEV __device__ __forceinline__

DEV unsigned short f2b(float f) {
  union { float f; unsigned u; } v; v.f = f;
  unsigned r = v.u + 0x7FFFu + ((v.u >> 16) & 1u);  // RNE
  return (unsigned short)(r >> 16);
}
DEV float b2f(unsigned short u) {
  union { unsigned u; float f; } v; v.u = ((unsigned)u) << 16;
  return v.f;
}

// ---------------- CSR build ----------------
__global__ void k_deg(const int* __restrict__ dst, int* __restrict__ deg, int E) {
  int e = blockIdx.x * 256 + threadIdx.x;
  if (e < E) atomicAdd(&deg[dst[e]], 1);
}

__global__ __launch_bounds__(256) void k_scan1(const int* __restrict__ deg,
    int* __restrict__ rowptr, int* __restrict__ bsum, int N) {
  __shared__ int sd[256];
  int b = blockIdx.x, tid = threadIdx.x;
  int i0 = b * 1024 + tid * 4;
  int v[4]; int s = 0;
#pragma unroll
  for (int j = 0; j < 4; j++) { int i = i0 + j; v[j] = (i < N) ? deg[i] : 0; s += v[j]; }
  sd[tid] = s;
  __syncthreads();
  for (int off = 1; off < 256; off <<= 1) {
    int t = (tid >= off) ? sd[tid - off] : 0;
    __syncthreads();
    sd[tid] += t;
    __syncthreads();
  }
  int run = sd[tid] - s;  // exclusive
#pragma unroll
  for (int j = 0; j < 4; j++) { int i = i0 + j; if (i < N) rowptr[i] = run; run += v[j]; }
  if (tid == 255) bsum[b] = sd[255];
}

__global__ __launch_bounds__(256) void k_scan2(int* __restrict__ bsum, int nb) {
  __shared__ int sd[256];
  int tid = threadIdx.x;
  int v = (tid < nb) ? bsum[tid] : 0;
  sd[tid] = v;
  __syncthreads();
  for (int off = 1; off < 256; off <<= 1) {
    int t = (tid >= off) ? sd[tid - off] : 0;
    __syncthreads();
    sd[tid] += t;
    __syncthreads();
  }
  if (tid < nb) bsum[tid] = sd[tid] - v;  // exclusive
}

__global__ __launch_bounds__(256) void k_scan3(int* __restrict__ rowptr,
    int* __restrict__ cursor, const int* __restrict__ bsum, int N, int E) {
  int b = blockIdx.x, tid = threadIdx.x;
  int add = bsum[b];
  int i0 = b * 1024 + tid * 4;
#pragma unroll
  for (int j = 0; j < 4; j++) {
    int i = i0 + j;
    if (i < N) { int r = rowptr[i] + add; rowptr[i] = r; cursor[i] = r; }
  }
  if (b == 0 && tid == 0) rowptr[N] = E;
}

__global__ void k_scatter(const int* __restrict__ src, const int* __restrict__ dst,
    int* __restrict__ cursor, int2* __restrict__ csr, int E) {
  int e = blockIdx.x * 256 + threadIdx.x;
  if (e < E) {
    int d = dst[e];
    int pos = atomicAdd(&cursor[d], 1);
    csr[pos] = make_int2(src[e], e);
  }
}

// ---------------- weight prep ----------------
__global__ void k_wt(const float* __restrict__ W, unsigned short* __restrict__ Wt,
                     int K, int Nout) {
  int idx = blockIdx.x * 256 + threadIdx.x;
  if (idx < K * Nout) {
    int n = idx / K, k = idx - n * K;
    Wt[idx] = f2b(W[(size_t)k * Nout + n]);
  }
}

// Wept[j][c], j = L*4+h (12 rows used, 16 total)
__global__ void k_wep(const float* __restrict__ We1, const float* __restrict__ ae1,
                      const float* __restrict__ We2, const float* __restrict__ ae2,
                      const float* __restrict__ We3, const float* __restrict__ ae3,
                      unsigned short* __restrict__ Wept) {
  int t = blockIdx.x * 256 + threadIdx.x;  // 0..767
  int j = t >> 6, c = t & 63;
  int L = j >> 2, h = j & 3;
  const float* We = (L == 0) ? We1 : (L == 1) ? We2 : We3;
  const float* ae = (L == 0) ? ae1 : (L == 1) ? ae2 : ae3;
  int C = (L == 2) ? 128 : 64;
  int HC = 4 * C;
  float s = 0.f;
  for (int cc = 0; cc < C; cc++) s += We[(size_t)c * HC + h * C + cc] * ae[h * C + cc];
  Wept[j * 64 + c] = f2b(s);
  if (t < 256) {
    int jj = 12 + (t >> 6);
    Wept[jj * 64 + (t & 63)] = 0;
  }
}

// ---------------- GEMM: C[M,Nout] = A[M,K] @ Bt[Nout,K]^T ----------------
// OUT_MODE: 0 = bf16 C; 2 = ale layer-major f32 ([L][EN][4], col=L*4+h, col<12)
// DO_ALD: epilogue also accumulates als/ald (head = n0*4/Nout, uniform per block)
template<bool A_F32, int OUT_MODE, bool DO_ALD>
__global__ __launch_bounds__(256) void k_gemm(const void* __restrict__ Ap,
    const unsigned short* __restrict__ Bt, void* __restrict__ Cp,
    int M, int Nout, int K, int EN,
    const float* __restrict__ a_s, const float* __restrict__ a_d,
    float* __restrict__ als, float* __restrict__ ald) {
  __shared__ unsigned short As[64][40];
  __shared__ unsigned short Bs[64][40];
  const int tid = threadIdx.x;
  const int wave = tid >> 6, lane = tid & 63;
  const int quad = lane >> 4, l16 = lane & 15;
  const int m0 = blockIdx.x * 64, n0 = blockIdx.y * 64;
  const int arow = tid >> 2, acg = (tid & 3) * 8;
  floatx4 acc[4] = {{0,0,0,0},{0,0,0,0},{0,0,0,0},{0,0,0,0}};
  for (int k0 = 0; k0 < K; k0 += 32) {
    {
      int gm = m0 + arow;
      unsigned short tmp[8];
      if (A_F32) {
        const float* Af = (const float*)Ap;
        if (gm < M) {
          const float4* p = (const float4*)(Af + (size_t)gm * K + k0 + acg);
          float4 u0 = p[0], u1 = p[1];
          tmp[0]=f2b(u0.x); tmp[1]=f2b(u0.y); tmp[2]=f2b(u0.z); tmp[3]=f2b(u0.w);
          tmp[4]=f2b(u1.x); tmp[5]=f2b(u1.y); tmp[6]=f2b(u1.z); tmp[7]=f2b(u1.w);
        } else {
#pragma unroll
          for (int j = 0; j < 8; j++) tmp[j] = 0;
        }
      } else {
        const unsigned short* Ab = (const unsigned short*)Ap;
        uint4 u = {0,0,0,0};
        if (gm < M) u = *(const uint4*)(Ab + (size_t)gm * K + k0 + acg);
        *(uint4*)tmp = u;
      }
      *(uint4*)&As[arow][acg] = *(uint4*)tmp;
      int gn = n0 + arow;
      uint4 bv = {0,0,0,0};
      if (gn < Nout) bv = *(const uint4*)(Bt + (size_t)gn * K + k0 + acg);
      *(uint4*)&Bs[arow][acg] = bv;
    }
    __syncthreads();
    short8 a = *(const short8*)&As[wave * 16 + l16][quad * 8];
#pragma unroll
    for (int t = 0; t < 4; t++) {
      short8 b = *(const short8*)&Bs[t * 16 + l16][quad * 8];
      acc[t] = __builtin_amdgcn_mfma_f32_16x16x32_bf16(a, b, acc[t], 0, 0, 0);
    }
    __syncthreads();
  }
#pragma unroll
  for (int t = 0; t < 4; t++) {
#pragma unroll
    for (int r = 0; r < 4; r++) {
      int row = m0 + wave * 16 + quad * 4 + r;  // C/D: col=lane&15, row=quad*4+reg
      int col = n0 + t * 16 + l16;
      float v = acc[t][r];
      if (OUT_MODE == 0) {
        if (row < M && col < Nout)
          ((unsigned short*)Cp)[(size_t)row * Nout + col] = f2b(v);
      } else {  // ale layer-major
        if (row < M && col < 12)
          ((float*)Cp)[((size_t)(col >> 2) * EN + row) * 4 + (col & 3)] = v;
      }
    }
  }
  if constexpr (DO_ALD) {
    int h = (n0 * 4) / Nout;
#pragma unroll
    for (int r = 0; r < 4; r++) {
      float ps = 0.f, pd = 0.f;
#pragma unroll
      for (int t = 0; t < 4; t++) {
        int col = n0 + t * 16 + l16;
        float v = acc[t][r];
        ps += v * a_s[col];
        pd += v * a_d[col];
      }
#pragma unroll
      for (int off = 1; off < 16; off <<= 1) {
        ps += __shfl_xor(ps, off, 64);
        pd += __shfl_xor(pd, off, 64);
      }
      int row = m0 + wave * 16 + quad * 4 + r;
      if (l16 == 0 && row < M) {
        atomicAdd(&als[row * 4 + h], ps);
        atomicAdd(&ald[row * 4 + h], pd);
      }
    }
  }
}

// ---------------- self-loop al_e = mean of incoming al_e ----------------
__global__ void k_loop_ale(const int* __restrict__ rowptr, const int2* __restrict__ csr,
                           float* __restrict__ ale, int N, int E) {
  int n = blockIdx.x * 256 + threadIdx.x;
  if (n >= N) return;
  const size_t EN = (size_t)E + N;
  int s = rowptr[n], e = rowptr[n + 1];
  float a[12];
#pragma unroll
  for (int j = 0; j < 12; j++) a[j] = 0.f;
  for (int p = s; p < e; p++) {
    int eid = csr[p].y;
#pragma unroll
    for (int L = 0; L < 3; L++) {
      float4 v = *(const float4*)(ale + (L * EN + eid) * 4);
      a[L * 4 + 0] += v.x; a[L * 4 + 1] += v.y;
      a[L * 4 + 2] += v.z; a[L * 4 + 3] += v.w;
    }
  }
  float inv = 1.0f / (float)((e - s) > 1 ? (e - s) : 1);
#pragma unroll
  for (int L = 0; L < 3; L++)
    *(float4*)(ale + (L * EN + E + n) * 4) =
        make_float4(a[L*4+0]*inv, a[L*4+1]*inv, a[L*4+2]*inv, a[L*4+3]*inv);
}

// ---------------- fused softmax + gather aggregation ----------------
// 16 lanes per node, 4 nodes per wave. No max-subtraction (|alpha| small),
// no LDS, no shuffles in main loop: per edge, lane computes p=exp(leaky(alpha))
// for its head from 4B gathers, accumulates denominator inline, and FMAs the
// hs row slice. U-deep unroll -> all loads of a chunk independent & in flight.
// MODE 0: concat heads, +bias, ReLU -> bf16. MODE 1: mean heads, +bias -> f32.
template<int VPL, int MODE>
__global__ __launch_bounds__(256) void k_gath(const unsigned short* __restrict__ hs,
    const int* __restrict__ rowptr, const int2* __restrict__ csr,
    const float* __restrict__ ale,  // layer base, [EN][4]
    const float* __restrict__ als, const float* __restrict__ ald,
    const float* __restrict__ bias, unsigned short* __restrict__ outb,
    float* __restrict__ outf, int N, int E) {
  constexpr int U = (VPL == 16) ? 8 : 4;
  constexpr int NV = VPL / 8;  // uint4 loads per edge per lane
  const int HC = 16 * VPL;
  const int lane = threadIdx.x & 63;
  const int grp = lane >> 4, sl = lane & 15, hd = sl >> 2;
  const int node = blockIdx.x * 16 + (threadIdx.x >> 6) * 4 + grp;
  if (node >= N) return;
  const int start = rowptr[node];
  const int cnt = rowptr[node + 1] - start;
  const float aldh = ald[node * 4 + hd];
  float acc[VPL];
#pragma unroll
  for (int j = 0; j < VPL; j++) acc[j] = 0.f;
  float den = 0.f;
  for (int base = 0; base < cnt; base += U) {
    int sp[U]; float pw[U];
#pragma unroll
    for (int e = 0; e < U; e++) {
      int idx = base + e;
      int idc = idx < cnt ? idx : cnt - 1;  // cnt >= 1 inside loop
      int2 se = csr[start + idc];
      sp[e] = se.x;
      float av = als[(size_t)se.x * 4 + hd] + aldh + ale[(size_t)se.y * 4 + hd];
      av = av > 0.f ? av : 0.2f * av;
      float p = __expf(av);
      pw[e] = idx < cnt ? p : 0.f;
    }
    uint4 dv[U][NV];
#pragma unroll
    for (int e = 0; e < U; e++) {
      const uint4* rp = (const uint4*)(hs + (size_t)sp[e] * HC + sl * VPL);
#pragma unroll
      for (int q = 0; q < NV; q++) dv[e][q] = rp[q];
    }
#pragma unroll
    for (int e = 0; e < U; e++) {
      den += pw[e];
      const unsigned short* vs = (const unsigned short*)&dv[e][0];
#pragma unroll
      for (int j = 0; j < VPL; j++) acc[j] += pw[e] * b2f(vs[j]);
    }
  }
  // self-loop
  {
    float av = als[(size_t)node * 4 + hd] + aldh + ale[((size_t)E + node) * 4 + hd];
    av = av > 0.f ? av : 0.2f * av;
    float p = __expf(av);
    den += p;
    const uint4* rp = (const uint4*)(hs + (size_t)node * HC + sl * VPL);
#pragma unroll
    for (int q = 0; q < NV; q++) {
      uint4 u = rp[q];
      const unsigned short* vs = (const unsigned short*)&u;
#pragma unroll
      for (int j = 0; j < 8; j++) acc[q * 8 + j] += p * b2f(vs[j]);
    }
  }
  float inv = 1.0f / (den + 1e-16f);
  if constexpr (MODE == 0) {
    unsigned short tmp[VPL];
#pragma unroll
    for (int j = 0; j < VPL; j++) {
      float v = acc[j] * inv + bias[sl * VPL + j];
      tmp[j] = f2b(fmaxf(v, 0.f));
    }
    unsigned short* op = outb + (size_t)node * HC + sl * VPL;
#pragma unroll
    for (int q = 0; q < NV; q++) ((uint4*)op)[q] = ((uint4*)tmp)[q];
  } else {
    // mean over heads: head = sl>>2; combine lanes sl^4, sl^8 (within 16-lane grp)
#pragma unroll
    for (int j = 0; j < VPL; j++) {
      float v = acc[j] * inv;
      v += __shfl_xor(v, 4, 64);
      v += __shfl_xor(v, 8, 64);
      acc[j] = v * 0.25f;
    }
    if (sl < 4) {
      float* op = outf + (size_t)node * (4 * VPL) + sl * VPL;
#pragma unroll
      for (int j = 0; j < VPL; j++) op[j] = acc[j] + bias[sl * VPL + j];
    }
  }
}

// ---------------- pooling (batch is sorted) ----------------
__global__ __launch_bounds__(256) void k_pool(const float* __restrict__ out3,
    const int* __restrict__ bat, float* __restrict__ g, int* __restrict__ cntb, int N) {
  int wid = blockIdx.x * 4 + (threadIdx.x >> 6);
  int lane = threadIdx.x & 63;
  int per = (N + 255) / 256;
  int s = wid * per, e = s + per;
  if (e > N) e = N;
  if (s >= e) return;
  int cur = bat[s];
  float ax = 0.f, ay = 0.f; int run = 0;
  for (int n = s; n < e; n++) {
    int b = bat[n];
    if (b != cur) {
      atomicAdd(&g[cur * 128 + lane * 2], ax);
      atomicAdd(&g[cur * 128 + lane * 2 + 1], ay);
      if (lane == 0) atomicAdd(&cntb[cur], run);
      ax = 0.f; ay = 0.f; run = 0; cur = b;
    }
    float2 v = *(const float2*)(out3 + (size_t)n * 128 + lane * 2);
    ax += v.x; ay += v.y; run++;
  }
  atomicAdd(&g[cur * 128 + lane * 2], ax);
  atomicAdd(&g[cur * 128 + lane * 2 + 1], ay);
  if (lane == 0) atomicAdd(&cntb[cur], run);
}

// ---------------- final head ----------------
__global__ __launch_bounds__(320) void k_final(const float* __restrict__ g,
    const int* __restrict__ cntb, const float* __restrict__ Wa, const float* __restrict__ ba,
    const float* __restrict__ Wv, const float* __restrict__ bv, float* __restrict__ out) {
  __shared__ float gm[128];
  int b = blockIdx.x, t = threadIdx.x;
  if (t < 128) {
    float c = (float)cntb[b];
    gm[t] = g[b * 128 + t] / fmaxf(c, 1.f);
  }
  __syncthreads();
  if (t < 257) {
    float acc = 0.f;
    if (t < 256) {
      for (int k = 0; k < 128; k++) acc += gm[k] * Wa[k * 256 + t];
      acc += ba[t];
    } else {
      for (int k = 0; k < 128; k++) acc += gm[k] * Wv[k];
      acc += bv[0];
    }
    out[b * 257 + t] = acc;
  }
}

extern "C" void kernel_launch(void* const* d_in, const int* in_sizes, int n_in,
                              void* d_out, int out_size, void* d_ws, size_t ws_size,
                              hipStream_t stream) {
  const float* x   = (const float*)d_in[0];
  const int*   ei  = (const int*)  d_in[1];
  const float* ea  = (const float*)d_in[2];
  const int*   bat = (const int*)  d_in[3];
  const float* W1  = (const float*)d_in[4];
  const float* as1 = (const float*)d_in[5];
  const float* ad1 = (const float*)d_in[6];
  const float* We1 = (const float*)d_in[7];
  const float* ae1 = (const float*)d_in[8];
  const float* b1  = (const float*)d_in[9];
  const float* W2  = (const float*)d_in[10];
  const float* as2 = (const float*)d_in[11];
  const float* ad2 = (const float*)d_in[12];
  const float* We2 = (const float*)d_in[13];
  const float* ae2 = (const float*)d_in[14];
  const float* b2  = (const float*)d_in[15];
  const float* W3  = (const float*)d_in[16];
  const float* as3 = (const float*)d_in[17];
  const float* ad3 = (const float*)d_in[18];
  const float* We3 = (const float*)d_in[19];
  const float* ae3 = (const float*)d_in[20];
  const float* b3  = (const float*)d_in[21];
  const float* Wa  = (const float*)d_in[22];
  const float* ba  = (const float*)d_in[23];
  const float* Wv  = (const float*)d_in[24];
  const float* bv  = (const float*)d_in[25];
  (void)n_in; (void)out_size; (void)ws_size;

  const int N = in_sizes[0] / 192;  // 50000
  const int E = in_sizes[1] / 2;    // 800000
  const size_t EN = (size_t)E + N;
  const int* srcv = ei;
  const int* dstv = ei + E;
  const int nb = (N + 1023) / 1024;

  size_t off = 0;
  auto alloc = [&](size_t bytes) -> char* {
    char* p = (char*)d_ws + off;
    off += (bytes + 255) & ~(size_t)255;
    return p;
  };
  int* deg     = (int*)alloc((size_t)N * 4);
  int* rowptr  = (int*)alloc((size_t)(N + 1) * 4);
  int* cursor  = (int*)alloc((size_t)N * 4);
  int* bsum    = (int*)alloc(256 * 4);
  int2* csr    = (int2*)alloc((size_t)E * 8);
  float* ale   = (float*)alloc(3 * EN * 4 * 4);  // [L][EN][4]
  unsigned short* Wept = (unsigned short*)alloc(16 * 64 * 2);
  unsigned short* W1t  = (unsigned short*)alloc(256 * 192 * 2);
  unsigned short* W2t  = (unsigned short*)alloc(256 * 256 * 2);
  unsigned short* W3t  = (unsigned short*)alloc(512 * 256 * 2);
  unsigned short* hs   = (unsigned short*)alloc((size_t)N * 512 * 2);
  unsigned short* h1   = (unsigned short*)alloc((size_t)N * 256 * 2);
  unsigned short* h2   = (unsigned short*)alloc((size_t)N * 256 * 2);
  float* out3  = (float*)alloc((size_t)N * 128 * 4);
  float* als_all = (float*)alloc((size_t)N * 4 * 4 * 6);  // als1,ald1,als2,ald2,als3,ald3
  float* g     = (float*)alloc(64 * 128 * 4 + 64 * 4);
  int* cntb    = (int*)(g + 64 * 128);
  float* als1 = als_all + (size_t)N * 4 * 0;
  float* ald1 = als_all + (size_t)N * 4 * 1;
  float* als2 = als_all + (size_t)N * 4 * 2;
  float* ald2 = als_all + (size_t)N * 4 * 3;
  float* als3 = als_all + (size_t)N * 4 * 4;
  float* ald3 = als_all + (size_t)N * 4 * 5;

  hipMemsetAsync(deg, 0, (size_t)N * 4, stream);
  hipMemsetAsync(als_all, 0, (size_t)N * 4 * 4 * 6, stream);
  hipMemsetAsync(g, 0, 64 * 128 * 4 + 64 * 4, stream);

  k_deg<<<(E + 255) / 256, 256, 0, stream>>>(dstv, deg, E);
  k_scan1<<<nb, 256, 0, stream>>>(deg, rowptr, bsum, N);
  k_scan2<<<1, 256, 0, stream>>>(bsum, nb);
  k_scan3<<<nb, 256, 0, stream>>>(rowptr, cursor, bsum, N, E);
  k_scatter<<<(E + 255) / 256, 256, 0, stream>>>(srcv, dstv, cursor, csr, E);
  k_wt<<<(192 * 256 + 255) / 256, 256, 0, stream>>>(W1, W1t, 192, 256);
  k_wt<<<(256 * 256 + 255) / 256, 256, 0, stream>>>(W2, W2t, 256, 256);
  k_wt<<<(256 * 512 + 255) / 256, 256, 0, stream>>>(W3, W3t, 256, 512);
  k_wep<<<3, 256, 0, stream>>>(We1, ae1, We2, ae2, We3, ae3, Wept);
  // al_e for all 3 layers in one GEMM over edge_attr (layer-major output)
  k_gemm<true, 2, false><<<dim3((E + 63) / 64, 1), 256, 0, stream>>>(
      ea, Wept, ale, E, 16, 64, (int)EN, nullptr, nullptr, nullptr, nullptr);
  k_loop_ale<<<(N + 255) / 256, 256, 0, stream>>>(rowptr, csr, ale, N, E);
  // layer 1
  k_gemm<true, 0, true><<<dim3((N + 63) / 64, 4), 256, 0, stream>>>(
      x, W1t, hs, N, 256, 192, 0, as1, ad1, als1, ald1);
  k_gath<16, 0><<<(N + 15) / 16, 256, 0, stream>>>(
      hs, rowptr, csr, ale + 0 * EN * 4, als1, ald1, b1, h1, nullptr, N, E);
  // layer 2
  k_gemm<false, 0, true><<<dim3((N + 63) / 64, 4), 256, 0, stream>>>(
      h1, W2t, hs, N, 256, 256, 0, as2, ad2, als2, ald2);
  k_gath<16, 0><<<(N + 15) / 16, 256, 0, stream>>>(
      hs, rowptr, csr, ale + 1 * EN * 4, als2, ald2, b2, h2, nullptr, N, E);
  // layer 3
  k_gemm<false, 0, true><<<dim3((N + 63) / 64, 8), 256, 0, stream>>>(
      h2, W3t, hs, N, 512, 256, 0, as3, ad3, als3, ald3);
  k_gath<32, 1><<<(N + 15) / 16, 256, 0, stream>>>(
      hs, rowptr, csr, ale + 2 * EN * 4, als3, ald3, b3, nullptr, out3, N, E);
  // pool + head
  k_pool<<<64, 256, 0, stream>>>(out3, bat, g, cntb, N);
  k_final<<<64, 320, 0, stream>>>(g, cntb, Wa, ba, Wv, bv, (float*)d_out);
}

// Round 4
// 1067.332 us; speedup vs baseline: 1.0753x; 1.0753x over previous
//
#include <hip/hip_runtime.h>
#include <hip/hip_bf16.h>

// GAT 3-layer + pool + dense head for MI355X (gfx950).
// R4: gather uses 64B-per-lane contiguous reads for ALL layers (8 lanes/node
// for HC=256, 16 lanes/node for HC=512) — layer-3's pattern ran ~2x faster
// at 32B/lane vs 64B/lane in R3 profiles. ale now edge-major [EN][16] so each
// edge's 12 attention logits live in one 64B sector.

typedef __attribute__((ext_vector_type(8))) short short8;
typedef __attribute__((ext_vector_type(4))) float floatx4;

#define DEV __device__ __forceinline__

DEV unsigned short f2b(float f) {
  union { float f; unsigned u; } v; v.f = f;
  unsigned r = v.u + 0x7FFFu + ((v.u >> 16) & 1u);  // RNE
  return (unsigned short)(r >> 16);
}
DEV float b2f(unsigned short u) {
  union { unsigned u; float f; } v; v.u = ((unsigned)u) << 16;
  return v.f;
}

// ---------------- CSR build ----------------
__global__ void k_deg(const int* __restrict__ dst, int* __restrict__ deg, int E) {
  int e = blockIdx.x * 256 + threadIdx.x;
  if (e < E) atomicAdd(&deg[dst[e]], 1);
}

__global__ __launch_bounds__(256) void k_scan1(const int* __restrict__ deg,
    int* __restrict__ rowptr, int* __restrict__ bsum, int N) {
  __shared__ int sd[256];
  int b = blockIdx.x, tid = threadIdx.x;
  int i0 = b * 1024 + tid * 4;
  int v[4]; int s = 0;
#pragma unroll
  for (int j = 0; j < 4; j++) { int i = i0 + j; v[j] = (i < N) ? deg[i] : 0; s += v[j]; }
  sd[tid] = s;
  __syncthreads();
  for (int off = 1; off < 256; off <<= 1) {
    int t = (tid >= off) ? sd[tid - off] : 0;
    __syncthreads();
    sd[tid] += t;
    __syncthreads();
  }
  int run = sd[tid] - s;  // exclusive
#pragma unroll
  for (int j = 0; j < 4; j++) { int i = i0 + j; if (i < N) rowptr[i] = run; run += v[j]; }
  if (tid == 255) bsum[b] = sd[255];
}

__global__ __launch_bounds__(256) void k_scan2(int* __restrict__ bsum, int nb) {
  __shared__ int sd[256];
  int tid = threadIdx.x;
  int v = (tid < nb) ? bsum[tid] : 0;
  sd[tid] = v;
  __syncthreads();
  for (int off = 1; off < 256; off <<= 1) {
    int t = (tid >= off) ? sd[tid - off] : 0;
    __syncthreads();
    sd[tid] += t;
    __syncthreads();
  }
  if (tid < nb) bsum[tid] = sd[tid] - v;  // exclusive
}

__global__ __launch_bounds__(256) void k_scan3(int* __restrict__ rowptr,
    int* __restrict__ cursor, const int* __restrict__ bsum, int N, int E) {
  int b = blockIdx.x, tid = threadIdx.x;
  int add = bsum[b];
  int i0 = b * 1024 + tid * 4;
#pragma unroll
  for (int j = 0; j < 4; j++) {
    int i = i0 + j;
    if (i < N) { int r = rowptr[i] + add; rowptr[i] = r; cursor[i] = r; }
  }
  if (b == 0 && tid == 0) rowptr[N] = E;
}

__global__ void k_scatter(const int* __restrict__ src, const int* __restrict__ dst,
    int* __restrict__ cursor, int2* __restrict__ csr, int E) {
  int e = blockIdx.x * 256 + threadIdx.x;
  if (e < E) {
    int d = dst[e];
    int pos = atomicAdd(&cursor[d], 1);
    csr[pos] = make_int2(src[e], e);
  }
}

// ---------------- weight prep ----------------
__global__ void k_wt(const float* __restrict__ W, unsigned short* __restrict__ Wt,
                     int K, int Nout) {
  int idx = blockIdx.x * 256 + threadIdx.x;
  if (idx < K * Nout) {
    int n = idx / K, k = idx - n * K;
    Wt[idx] = f2b(W[(size_t)k * Nout + n]);
  }
}

// Wept[j][c], j = L*4+h (12 rows used, 16 total)
__global__ void k_wep(const float* __restrict__ We1, const float* __restrict__ ae1,
                      const float* __restrict__ We2, const float* __restrict__ ae2,
                      const float* __restrict__ We3, const float* __restrict__ ae3,
                      unsigned short* __restrict__ Wept) {
  int t = blockIdx.x * 256 + threadIdx.x;  // 0..767
  int j = t >> 6, c = t & 63;
  int L = j >> 2, h = j & 3;
  const float* We = (L == 0) ? We1 : (L == 1) ? We2 : We3;
  const float* ae = (L == 0) ? ae1 : (L == 1) ? ae2 : ae3;
  int C = (L == 2) ? 128 : 64;
  int HC = 4 * C;
  float s = 0.f;
  for (int cc = 0; cc < C; cc++) s += We[(size_t)c * HC + h * C + cc] * ae[h * C + cc];
  Wept[j * 64 + c] = f2b(s);
  if (t < 256) {
    int jj = 12 + (t >> 6);
    Wept[jj * 64 + (t & 63)] = 0;
  }
}

// ---------------- GEMM: C[M,Nout] = A[M,K] @ Bt[Nout,K]^T ----------------
// OUT_MODE: 0 = bf16 C; 2 = ale edge-major f32 ([M][16], col<12)
// DO_ALD: epilogue also accumulates als/ald (head = n0*4/Nout, uniform per block)
template<bool A_F32, int OUT_MODE, bool DO_ALD>
__global__ __launch_bounds__(256) void k_gemm(const void* __restrict__ Ap,
    const unsigned short* __restrict__ Bt, void* __restrict__ Cp,
    int M, int Nout, int K,
    const float* __restrict__ a_s, const float* __restrict__ a_d,
    float* __restrict__ als, float* __restrict__ ald) {
  __shared__ unsigned short As[64][40];
  __shared__ unsigned short Bs[64][40];
  const int tid = threadIdx.x;
  const int wave = tid >> 6, lane = tid & 63;
  const int quad = lane >> 4, l16 = lane & 15;
  const int m0 = blockIdx.x * 64, n0 = blockIdx.y * 64;
  const int arow = tid >> 2, acg = (tid & 3) * 8;
  floatx4 acc[4] = {{0,0,0,0},{0,0,0,0},{0,0,0,0},{0,0,0,0}};
  for (int k0 = 0; k0 < K; k0 += 32) {
    {
      int gm = m0 + arow;
      unsigned short tmp[8];
      if (A_F32) {
        const float* Af = (const float*)Ap;
        if (gm < M) {
          const float4* p = (const float4*)(Af + (size_t)gm * K + k0 + acg);
          float4 u0 = p[0], u1 = p[1];
          tmp[0]=f2b(u0.x); tmp[1]=f2b(u0.y); tmp[2]=f2b(u0.z); tmp[3]=f2b(u0.w);
          tmp[4]=f2b(u1.x); tmp[5]=f2b(u1.y); tmp[6]=f2b(u1.z); tmp[7]=f2b(u1.w);
        } else {
#pragma unroll
          for (int j = 0; j < 8; j++) tmp[j] = 0;
        }
      } else {
        const unsigned short* Ab = (const unsigned short*)Ap;
        uint4 u = {0,0,0,0};
        if (gm < M) u = *(const uint4*)(Ab + (size_t)gm * K + k0 + acg);
        *(uint4*)tmp = u;
      }
      *(uint4*)&As[arow][acg] = *(uint4*)tmp;
      int gn = n0 + arow;
      uint4 bv = {0,0,0,0};
      if (gn < Nout) bv = *(const uint4*)(Bt + (size_t)gn * K + k0 + acg);
      *(uint4*)&Bs[arow][acg] = bv;
    }
    __syncthreads();
    short8 a = *(const short8*)&As[wave * 16 + l16][quad * 8];
#pragma unroll
    for (int t = 0; t < 4; t++) {
      short8 b = *(const short8*)&Bs[t * 16 + l16][quad * 8];
      acc[t] = __builtin_amdgcn_mfma_f32_16x16x32_bf16(a, b, acc[t], 0, 0, 0);
    }
    __syncthreads();
  }
#pragma unroll
  for (int t = 0; t < 4; t++) {
#pragma unroll
    for (int r = 0; r < 4; r++) {
      int row = m0 + wave * 16 + quad * 4 + r;  // C/D: col=lane&15, row=quad*4+reg
      int col = n0 + t * 16 + l16;
      float v = acc[t][r];
      if (OUT_MODE == 0) {
        if (row < M && col < Nout)
          ((unsigned short*)Cp)[(size_t)row * Nout + col] = f2b(v);
      } else {  // ale edge-major [M][16]
        if (row < M && col < 12)
          ((float*)Cp)[(size_t)row * 16 + col] = v;
      }
    }
  }
  if constexpr (DO_ALD) {
    int h = (n0 * 4) / Nout;
#pragma unroll
    for (int r = 0; r < 4; r++) {
      float ps = 0.f, pd = 0.f;
#pragma unroll
      for (int t = 0; t < 4; t++) {
        int col = n0 + t * 16 + l16;
        float v = acc[t][r];
        ps += v * a_s[col];
        pd += v * a_d[col];
      }
#pragma unroll
      for (int off = 1; off < 16; off <<= 1) {
        ps += __shfl_xor(ps, off, 64);
        pd += __shfl_xor(pd, off, 64);
      }
      int row = m0 + wave * 16 + quad * 4 + r;
      if (l16 == 0 && row < M) {
        atomicAdd(&als[row * 4 + h], ps);
        atomicAdd(&ald[row * 4 + h], pd);
      }
    }
  }
}

// ---------------- self-loop al_e = mean of incoming al_e ----------------
// 4 lanes per node; lane q<3 accumulates float4 q of the edge's 64B ale sector.
__global__ __launch_bounds__(256) void k_loop_ale(const int* __restrict__ rowptr,
    const int2* __restrict__ csr, float* __restrict__ ale, int N, int E) {
  int t = blockIdx.x * 256 + threadIdx.x;
  int node = t >> 2, q = t & 3;
  if (node >= N) return;
  int s = rowptr[node], e = rowptr[node + 1];
  float4 a = make_float4(0.f, 0.f, 0.f, 0.f);
  if (q < 3) {
    for (int p = s; p < e; p++) {
      int eid = csr[p].y;
      float4 v = *(const float4*)(ale + (size_t)eid * 16 + q * 4);
      a.x += v.x; a.y += v.y; a.z += v.z; a.w += v.w;
    }
  }
  float inv = 1.0f / (float)((e - s) > 1 ? (e - s) : 1);
  if (q < 3)
    *(float4*)(ale + ((size_t)E + node) * 16 + q * 4) =
        make_float4(a.x * inv, a.y * inv, a.z * inv, a.w * inv);
}

// ---------------- fused softmax + gather aggregation ----------------
// LPN lanes per node, each lane owns VPL features (64B contiguous per row).
// No max-subtraction (|alpha| small), no LDS/shuffles in main loop.
// MODE 0: concat heads, +bias, ReLU -> bf16. MODE 1: mean heads, +bias -> f32.
template<int LPN, int VPL, int MODE>
__global__ __launch_bounds__(256) void k_gath(const unsigned short* __restrict__ hs,
    const int* __restrict__ rowptr, const int2* __restrict__ csr,
    const float* __restrict__ ale,  // [EN][16], layer offset L4
    int L4,
    const float* __restrict__ als, const float* __restrict__ ald,
    const float* __restrict__ bias, unsigned short* __restrict__ outb,
    float* __restrict__ outf, int N, int E) {
  constexpr int U = 4;
  constexpr int NV = VPL / 8;        // uint4 loads per edge per lane (4)
  constexpr int HC = LPN * VPL;      // features per node
  constexpr int SH = (LPN == 8) ? 1 : 2;  // head = sl >> SH
  constexpr int NPB = 256 / LPN;     // nodes per block
  const int lane = threadIdx.x & 63;
  const int sl = lane & (LPN - 1);
  const int grp = lane / LPN;
  const int hd = sl >> SH;
  const int node = blockIdx.x * NPB + (threadIdx.x >> 6) * (64 / LPN) + grp;
  if (node >= N) return;
  const int start = rowptr[node];
  const int cnt = rowptr[node + 1] - start;
  const float aldh = ald[node * 4 + hd];
  float acc[VPL];
#pragma unroll
  for (int j = 0; j < VPL; j++) acc[j] = 0.f;
  float den = 0.f;
  for (int base = 0; base < cnt; base += U) {
    int sp[U]; float pw[U];
#pragma unroll
    for (int e = 0; e < U; e++) {
      int idx = base + e;
      int idc = idx < cnt ? idx : cnt - 1;  // cnt >= 1 inside loop
      int2 se = csr[start + idc];
      sp[e] = se.x;
      float av = als[(size_t)se.x * 4 + hd] + aldh +
                 ale[(size_t)se.y * 16 + L4 + hd];
      av = av > 0.f ? av : 0.2f * av;
      float p = __expf(av);
      pw[e] = idx < cnt ? p : 0.f;
    }
    uint4 dv[U][NV];
#pragma unroll
    for (int e = 0; e < U; e++) {
      const uint4* rp = (const uint4*)(hs + (size_t)sp[e] * HC + sl * VPL);
#pragma unroll
      for (int q = 0; q < NV; q++) dv[e][q] = rp[q];
    }
#pragma unroll
    for (int e = 0; e < U; e++) {
      den += pw[e];
      const unsigned short* vs = (const unsigned short*)&dv[e][0];
#pragma unroll
      for (int j = 0; j < VPL; j++) acc[j] += pw[e] * b2f(vs[j]);
    }
  }
  // self-loop
  {
    float av = als[(size_t)node * 4 + hd] + aldh +
               ale[((size_t)E + node) * 16 + L4 + hd];
    av = av > 0.f ? av : 0.2f * av;
    float p = __expf(av);
    den += p;
    const uint4* rp = (const uint4*)(hs + (size_t)node * HC + sl * VPL);
#pragma unroll
    for (int q = 0; q < NV; q++) {
      uint4 u = rp[q];
      const unsigned short* vs = (const unsigned short*)&u;
#pragma unroll
      for (int j = 0; j < 8; j++) acc[q * 8 + j] += p * b2f(vs[j]);
    }
  }
  float inv = 1.0f / (den + 1e-16f);
  if constexpr (MODE == 0) {
    unsigned short tmp[VPL];
#pragma unroll
    for (int j = 0; j < VPL; j++) {
      float v = acc[j] * inv + bias[sl * VPL + j];
      tmp[j] = f2b(fmaxf(v, 0.f));
    }
    unsigned short* op = outb + (size_t)node * HC + sl * VPL;
#pragma unroll
    for (int q = 0; q < NV; q++) ((uint4*)op)[q] = ((uint4*)tmp)[q];
  } else {
    // LPN=16: head = sl>>2; combine lanes sl^4, sl^8 (across 4 heads)
#pragma unroll
    for (int j = 0; j < VPL; j++) {
      float v = acc[j] * inv;
      v += __shfl_xor(v, 4, 64);
      v += __shfl_xor(v, 8, 64);
      acc[j] = v * 0.25f;
    }
    if (sl < 4) {
      float* op = outf + (size_t)node * (4 * VPL) + sl * VPL;
#pragma unroll
      for (int j = 0; j < VPL; j++) op[j] = acc[j] + bias[sl * VPL + j];
    }
  }
}

// ---------------- pooling (batch is sorted) ----------------
__global__ __launch_bounds__(256) void k_pool(const float* __restrict__ out3,
    const int* __restrict__ bat, float* __restrict__ g, int* __restrict__ cntb, int N) {
  int wid = blockIdx.x * 4 + (threadIdx.x >> 6);
  int lane = threadIdx.x & 63;
  int per = (N + 255) / 256;
  int s = wid * per, e = s + per;
  if (e > N) e = N;
  if (s >= e) return;
  int cur = bat[s];
  float ax = 0.f, ay = 0.f; int run = 0;
  for (int n = s; n < e; n++) {
    int b = bat[n];
    if (b != cur) {
      atomicAdd(&g[cur * 128 + lane * 2], ax);
      atomicAdd(&g[cur * 128 + lane * 2 + 1], ay);
      if (lane == 0) atomicAdd(&cntb[cur], run);
      ax = 0.f; ay = 0.f; run = 0; cur = b;
    }
    float2 v = *(const float2*)(out3 + (size_t)n * 128 + lane * 2);
    ax += v.x; ay += v.y; run++;
  }
  atomicAdd(&g[cur * 128 + lane * 2], ax);
  atomicAdd(&g[cur * 128 + lane * 2 + 1], ay);
  if (lane == 0) atomicAdd(&cntb[cur], run);
}

// ---------------- final head ----------------
__global__ __launch_bounds__(320) void k_final(const float* __restrict__ g,
    const int* __restrict__ cntb, const float* __restrict__ Wa, const float* __restrict__ ba,
    const float* __restrict__ Wv, const float* __restrict__ bv, float* __restrict__ out) {
  __shared__ float gm[128];
  int b = blockIdx.x, t = threadIdx.x;
  if (t < 128) {
    float c = (float)cntb[b];
    gm[t] = g[b * 128 + t] / fmaxf(c, 1.f);
  }
  __syncthreads();
  if (t < 257) {
    float acc = 0.f;
    if (t < 256) {
      for (int k = 0; k < 128; k++) acc += gm[k] * Wa[k * 256 + t];
      acc += ba[t];
    } else {
      for (int k = 0; k < 128; k++) acc += gm[k] * Wv[k];
      acc += bv[0];
    }
    out[b * 257 + t] = acc;
  }
}

extern "C" void kernel_launch(void* const* d_in, const int* in_sizes, int n_in,
                              void* d_out, int out_size, void* d_ws, size_t ws_size,
                              hipStream_t stream) {
  const float* x   = (const float*)d_in[0];
  const int*   ei  = (const int*)  d_in[1];
  const float* ea  = (const float*)d_in[2];
  const int*   bat = (const int*)  d_in[3];
  const float* W1  = (const float*)d_in[4];
  const float* as1 = (const float*)d_in[5];
  const float* ad1 = (const float*)d_in[6];
  const float* We1 = (const float*)d_in[7];
  const float* ae1 = (const float*)d_in[8];
  const float* b1  = (const float*)d_in[9];
  const float* W2  = (const float*)d_in[10];
  const float* as2 = (const float*)d_in[11];
  const float* ad2 = (const float*)d_in[12];
  const float* We2 = (const float*)d_in[13];
  const float* ae2 = (const float*)d_in[14];
  const float* b2  = (const float*)d_in[15];
  const float* W3  = (const float*)d_in[16];
  const float* as3 = (const float*)d_in[17];
  const float* ad3 = (const float*)d_in[18];
  const float* We3 = (const float*)d_in[19];
  const float* ae3 = (const float*)d_in[20];
  const float* b3  = (const float*)d_in[21];
  const float* Wa  = (const float*)d_in[22];
  const float* ba  = (const float*)d_in[23];
  const float* Wv  = (const float*)d_in[24];
  const float* bv  = (const float*)d_in[25];
  (void)n_in; (void)out_size; (void)ws_size;

  const int N = in_sizes[0] / 192;  // 50000
  const int E = in_sizes[1] / 2;    // 800000
  const size_t EN = (size_t)E + N;
  const int* srcv = ei;
  const int* dstv = ei + E;
  const int nb = (N + 1023) / 1024;

  size_t off = 0;
  auto alloc = [&](size_t bytes) -> char* {
    char* p = (char*)d_ws + off;
    off += (bytes + 255) & ~(size_t)255;
    return p;
  };
  int* deg     = (int*)alloc((size_t)N * 4);
  int* rowptr  = (int*)alloc((size_t)(N + 1) * 4);
  int* cursor  = (int*)alloc((size_t)N * 4);
  int* bsum    = (int*)alloc(256 * 4);
  int2* csr    = (int2*)alloc((size_t)E * 8);
  float* ale   = (float*)alloc(EN * 16 * 4);  // [EN][16] edge-major, 12 used
  unsigned short* Wept = (unsigned short*)alloc(16 * 64 * 2);
  unsigned short* W1t  = (unsigned short*)alloc(256 * 192 * 2);
  unsigned short* W2t  = (unsigned short*)alloc(256 * 256 * 2);
  unsigned short* W3t  = (unsigned short*)alloc(512 * 256 * 2);
  unsigned short* hs   = (unsigned short*)alloc((size_t)N * 512 * 2);
  unsigned short* h1   = (unsigned short*)alloc((size_t)N * 256 * 2);
  unsigned short* h2   = (unsigned short*)alloc((size_t)N * 256 * 2);
  float* out3  = (float*)alloc((size_t)N * 128 * 4);
  float* als_all = (float*)alloc((size_t)N * 4 * 4 * 6);
  float* g     = (float*)alloc(64 * 128 * 4 + 64 * 4);
  int* cntb    = (int*)(g + 64 * 128);
  float* als1 = als_all + (size_t)N * 4 * 0;
  float* ald1 = als_all + (size_t)N * 4 * 1;
  float* als2 = als_all + (size_t)N * 4 * 2;
  float* ald2 = als_all + (size_t)N * 4 * 3;
  float* als3 = als_all + (size_t)N * 4 * 4;
  float* ald3 = als_all + (size_t)N * 4 * 5;

  hipMemsetAsync(deg, 0, (size_t)N * 4, stream);
  hipMemsetAsync(als_all, 0, (size_t)N * 4 * 4 * 6, stream);
  hipMemsetAsync(g, 0, 64 * 128 * 4 + 64 * 4, stream);

  k_deg<<<(E + 255) / 256, 256, 0, stream>>>(dstv, deg, E);
  k_scan1<<<nb, 256, 0, stream>>>(deg, rowptr, bsum, N);
  k_scan2<<<1, 256, 0, stream>>>(bsum, nb);
  k_scan3<<<nb, 256, 0, stream>>>(rowptr, cursor, bsum, N, E);
  k_scatter<<<(E + 255) / 256, 256, 0, stream>>>(srcv, dstv, cursor, csr, E);
  k_wt<<<(192 * 256 + 255) / 256, 256, 0, stream>>>(W1, W1t, 192, 256);
  k_wt<<<(256 * 256 + 255) / 256, 256, 0, stream>>>(W2, W2t, 256, 256);
  k_wt<<<(256 * 512 + 255) / 256, 256, 0, stream>>>(W3, W3t, 256, 512);
  k_wep<<<3, 256, 0, stream>>>(We1, ae1, We2, ae2, We3, ae3, Wept);
  // al_e for all 3 layers in one GEMM over edge_attr (edge-major output)
  k_gemm<true, 2, false><<<dim3((E + 63) / 64, 1), 256, 0, stream>>>(
      ea, Wept, ale, E, 16, 64, nullptr, nullptr, nullptr, nullptr);
  k_loop_ale<<<(N * 4 + 255) / 256, 256, 0, stream>>>(rowptr, csr, ale, N, E);
  // layer 1
  k_gemm<true, 0, true><<<dim3((N + 63) / 64, 4), 256, 0, stream>>>(
      x, W1t, hs, N, 256, 192, as1, ad1, als1, ald1);
  k_gath<8, 32, 0><<<(N + 31) / 32, 256, 0, stream>>>(
      hs, rowptr, csr, ale, 0, als1, ald1, b1, h1, nullptr, N, E);
  // layer 2
  k_gemm<false, 0, true><<<dim3((N + 63) / 64, 4), 256, 0, stream>>>(
      h1, W2t, hs, N, 256, 256, as2, ad2, als2, ald2);
  k_gath<8, 32, 0><<<(N + 31) / 32, 256, 0, stream>>>(
      hs, rowptr, csr, ale, 4, als2, ald2, b2, h2, nullptr, N, E);
  // layer 3
  k_gemm<false, 0, true><<<dim3((N + 63) / 64, 8), 256, 0, stream>>>(
      h2, W3t, hs, N, 512, 256, as3, ad3, als3, ald3);
  k_gath<16, 32, 1><<<(N + 15) / 16, 256, 0, stream>>>(
      hs, rowptr, csr, ale, 8, als3, ald3, b3, nullptr, out3, N, E);
  // pool + head
  k_pool<<<64, 256, 0, stream>>>(out3, bat, g, cntb, N);
  k_final<<<64, 320, 0, stream>>>(g, cntb, Wa, ba, Wv, bv, (float*)d_out);
}